// Round 1
// 368.841 us; speedup vs baseline: 1.0517x; 1.0517x over previous
//
#include <hip/hip_runtime.h>
#include <cstdint>
#include <cstddef>

typedef unsigned short u16;
typedef __attribute__((ext_vector_type(8))) __bf16 bf16x8;
typedef __attribute__((ext_vector_type(4))) float floatx4;

#define Bz 8
#define Sz 1024
#define Dz 768
#define Hz 12
#define DHz 64

__device__ __forceinline__ u16 f2b(float f) {
  unsigned u = __float_as_uint(f);
  return (u16)((u + 0x7fffu + ((u >> 16) & 1u)) >> 16);
}

__device__ __forceinline__ bf16x8 ld8(const u16* p) {
  union { uint4 u; bf16x8 b; } t;
  t.u = *reinterpret_cast<const uint4*>(p);
  return t.b;
}

// async global->LDS, 16B per lane; lds base must be wave-uniform (HW adds lane*16)
__device__ __forceinline__ void load_lds16(const u16* g, u16* l) {
  __builtin_amdgcn_global_load_lds(
      (const __attribute__((address_space(1))) unsigned int*)g,
      (__attribute__((address_space(3))) unsigned int*)l, 16, 0, 0);
}

// ---------------- conversions ----------------
__global__ __launch_bounds__(256) void cvt4(const float* __restrict__ src,
                                            u16* __restrict__ dst, int n4) {
  int i = blockIdx.x * 256 + threadIdx.x;
  if (i >= n4) return;
  float4 v = reinterpret_cast<const float4*>(src)[i];
  union { u16 s[4]; uint2 u; } t;
  t.s[0] = f2b(v.x); t.s[1] = f2b(v.y); t.s[2] = f2b(v.z); t.s[3] = f2b(v.w);
  reinterpret_cast<uint2*>(dst)[i] = t.u;
}

// transpose fp32 [K][N] -> bf16 [N][K]; for QKV pack s1/s2 select by column
__global__ __launch_bounds__(256)
void wtrans(const float* __restrict__ s0, const float* __restrict__ s1,
            const float* __restrict__ s2, u16* __restrict__ dst,
            int K, int N, int srcN) {
  __shared__ float T[32][33];
  const int tx = threadIdx.x & 31, ty = threadIdx.x >> 5;
  const int n0 = blockIdx.x * 32, k0 = blockIdx.y * 32;
  const int n = n0 + tx;
  const float* src = s0;
  int nn = n;
  if (s1 && n >= 1536) { src = s2; nn = n - 1536; }
  else if (s1 && n >= 768) { src = s1; nn = n - 768; }
#pragma unroll
  for (int i = 0; i < 4; ++i)
    T[ty + i * 8][tx] = src[(size_t)(k0 + ty + i * 8) * srcN + nn];
  __syncthreads();
#pragma unroll
  for (int i = 0; i < 4; ++i)
    dst[(size_t)(n0 + ty + i * 8) * K + k0 + tx] = f2b(T[tx][ty + i * 8]);
}

// ---------------- GEMM (B^T input): C = A(MxK) * Bt(NxK)^T + epilogue ------
// R6: 3-buffer LDS, 2-tiles-ahead prefetch, counted s_waitcnt vmcnt(4) at the
// loop head (vmcnt(0) only on the final iteration).  Tile i is issued at
// iteration i-2, so the wait has ~2 full iterations of latency slack instead
// of <1.  Prefetch stays BELOW the frag ds_reads (proven order: any
// compiler-inserted conservative VMEM->LDS drain before the ds_reads then
// degrades us to the old schedule, never worse).
// Bank-conflict fix: fragment reads of the [128][32] row-major tile put the
// 16 lanes of each quad-class on a 2-bank window (8-way).  We XOR the 16B
// chunk index with (row>>1)&3.  global_load_lds writes linearly, so the
// swizzle is applied on the GLOBAL source chunk per lane (rule: linear dest +
// inverse-swizzled source + swizzled read).  For this staging layout the row
// key collapses to (lane>>3)&3 on the write and (l15>>1)&3 on the read.
// XCD swizzle: all grids have nwg%8==0; contiguous swz chunks per XCD keep
// the B panel (and 8 A row-panels) resident in one XCD's 4MB L2.
// EPI 0: QKV scatter; EPI 1: bias0 + resid (fp32) -> outF; EPI 2: bias0+relu->outB
template <int EPI>
__global__ __launch_bounds__(256, 3)
void gemm_k(const u16* __restrict__ A, const u16* __restrict__ Bt,
            int M, int N, int K,
            const float* __restrict__ bias0, const float* __restrict__ bias1,
            const float* __restrict__ bias2, const float* __restrict__ resid,
            float* __restrict__ outF, u16* __restrict__ outB,
            u16* __restrict__ qO, u16* __restrict__ kO, u16* __restrict__ vtO) {
  __shared__ __align__(16) u16 As[3][128 * 32];
  __shared__ __align__(16) u16 Bs[3][128 * 32];
  const int tid = threadIdx.x;
  const int lane = tid & 63, wave = tid >> 6;
  const int l15 = lane & 15, quad = lane >> 4;

  // bijective XCD-aware remap of the linear workgroup id
  const int nx = gridDim.x;
  const int nwg = nx * gridDim.y;
  const int lin = blockIdx.y * nx + blockIdx.x;
  const int swz = (lin & 7) * (nwg >> 3) + (lin >> 3);
  const int bx = swz % nx, by = swz / nx;

  const int m0 = by * 128, n0 = bx * 128;
  const int wm = (wave >> 1) * 64, wn = (wave & 1) * 64;

  floatx4 acc[4][4];
#pragma unroll
  for (int i = 0; i < 4; ++i)
#pragma unroll
    for (int j = 0; j < 4; ++j) acc[i][j] = {0.f, 0.f, 0.f, 0.f};

  const int srow = lane >> 2;          // + (wave*2+j)*16
  // pre-swizzled source chunk: position (lane&3) holds chunk (lane&3)^key,
  // key = ((subtile_row)>>1)&3 = (lane>>3)&3 here (subtile base is 16-row aligned)
  const int scol = (((lane & 3) ^ ((lane >> 3) & 3))) * 8;
  const u16* pA = A + (size_t)(m0 + wave * 32 + srow) * K + scol;
  const u16* pB = Bt + (size_t)(n0 + wave * 32 + srow) * K + scol;

  // prologue: stage tiles 0 and 1 into bufs 0,1 (8 loads/thread in flight,
  // tile 0 = oldest 4, tile 1 = next 4 — vmcnt counting relies on this order)
#pragma unroll
  for (int t = 0; t < 2; ++t)
#pragma unroll
    for (int j = 0; j < 2; ++j) {
      load_lds16(pA + (size_t)(j * 16) * K + t * 32, &As[t][(wave * 2 + j) * 512]);
      load_lds16(pB + (size_t)(j * 16) * K + t * 32, &Bs[t][(wave * 2 + j) * 512]);
    }

  const int NIT = K >> 5;
  const int rsw = (l15 >> 1) & 3;      // read-side bank swizzle key
  int cur = 0;
  for (int i = 0; i < NIT; ++i) {
    // tile i landed (leave tile i+1's 4 loads in flight); wait must precede
    // the barrier for cross-wave LDS visibility.
    if (i == NIT - 1) asm volatile("s_waitcnt vmcnt(0)" ::: "memory");
    else              asm volatile("s_waitcnt vmcnt(4)" ::: "memory");
    __builtin_amdgcn_s_barrier();
    bf16x8 af[4], bf[4];
#pragma unroll
    for (int ii = 0; ii < 4; ++ii)
      af[ii] = ld8(&As[cur][(wm + ii * 16 + l15) * 32 + (quad ^ rsw) * 8]);
#pragma unroll
    for (int j = 0; j < 4; ++j)
      bf[j] = ld8(&Bs[cur][(wn + j * 16 + l15) * 32 + (quad ^ rsw) * 8]);
    // keep the prefetch BELOW the ds_reads in the final schedule
    __builtin_amdgcn_sched_barrier(0);
    if (i + 2 < NIT) {
      const int k2 = (i + 2) << 5;
      int pf = cur + 2; if (pf >= 3) pf -= 3;
#pragma unroll
      for (int j = 0; j < 2; ++j) {
        load_lds16(pA + (size_t)(j * 16) * K + k2, &As[pf][(wave * 2 + j) * 512]);
        load_lds16(pB + (size_t)(j * 16) * K + k2, &Bs[pf][(wave * 2 + j) * 512]);
      }
    }
    __builtin_amdgcn_sched_barrier(0);
#pragma unroll
    for (int ii = 0; ii < 4; ++ii)
#pragma unroll
      for (int j = 0; j < 4; ++j)
        acc[ii][j] = __builtin_amdgcn_mfma_f32_16x16x32_bf16(af[ii], bf[j],
                                                             acc[ii][j], 0, 0, 0);
    cur += 1; if (cur == 3) cur = 0;
  }

#pragma unroll
  for (int i = 0; i < 4; ++i) {
    int mbase = m0 + wm + i * 16 + quad * 4;
#pragma unroll
    for (int j = 0; j < 4; ++j) {
      int n = n0 + wn + j * 16 + l15;
#pragma unroll
      for (int r = 0; r < 4; ++r) {
        int mm = mbase + r;
        float v = acc[i][j][r];
        if (EPI == 0) {
          if (n < 768) {
            v += bias0[n];
            qO[(size_t)mm * 768 + n] = f2b(v);
          } else if (n < 1536) {
            v += bias1[n - 768];
            kO[(size_t)mm * 768 + (n - 768)] = f2b(v);
          } else {
            int d = n - 1536;
            v += bias2[d];
            int hh = d >> 6, dh = d & 63;
            int bb = mm >> 10, ss = mm & 1023;
            vtO[((size_t)(bb * Hz + hh) * DHz + dh) * Sz + ss] = f2b(v);
          }
        } else if (EPI == 1) {
          v += bias0[n] + resid[(size_t)mm * N + n];
          outF[(size_t)mm * N + n] = v;
        } else {
          v += bias0[n];
          v = fmaxf(v, 0.f);
          outB[(size_t)mm * N + n] = f2b(v);
        }
      }
    }
  }
}

// ---------------- flash attention (LDS-staged K/V tiles) ----------------
__global__ __launch_bounds__(256, 3)
void attn_k(const u16* __restrict__ q, const u16* __restrict__ kbuf,
            const u16* __restrict__ vt, const int* __restrict__ mask,
            u16* __restrict__ ctx) {
  __shared__ float addend[Sz];
  __shared__ __align__(16) u16 Ks[128 * 64];
  __shared__ __align__(16) u16 Vs[64 * 128];
  __shared__ __align__(16) u16 P[4][16][132];
  const int tid = threadIdx.x;
  const int wave = tid >> 6, lane = tid & 63;
  const int l15 = lane & 15, quad = lane >> 4;
  // XCD swizzle: grid is (16, 96) = 1536 wgs; 192 consecutive swz per XCD
  // -> 12 (b,h) groups' K/V (~3MB) stay in one XCD's L2.
  const int lin = blockIdx.y * 16 + blockIdx.x;
  const int swzid = (lin & 7) * 192 + (lin >> 3);
  const int bq = swzid & 15;
  const int bh = swzid >> 4;
  const int b = bh / Hz, h = bh - b * Hz;

  for (int s = tid; s < Sz; s += 256)
    addend[s] = mask[b * Sz + s] ? 0.f : -1e9f;

  const int qrow = bq * 64 + wave * 16 + l15;
  const u16* qp = q + (size_t)(b * Sz + qrow) * Dz + h * DHz;
  const bf16x8 fq0 = ld8(qp + quad * 8);
  const bf16x8 fq1 = ld8(qp + 32 + quad * 8);

  const int kchunk = (lane & 7) ^ (lane >> 3);
  const int l7 = l15 & 7;
  const int s0q = quad ^ l7;

  float m_l = -1e30f, l_l = 0.f;
  floatx4 o[4];
#pragma unroll
  for (int nt = 0; nt < 4; ++nt) o[nt] = {0.f, 0.f, 0.f, 0.f};

  const size_t vbase = (size_t)(b * Hz + h) * DHz * Sz;

  for (int kt = 0; kt < Sz / 128; ++kt) {
    __syncthreads();
#pragma unroll
    for (int j = 0; j < 4; ++j) {
      const int key = wave * 32 + j * 8 + (lane >> 3);
      load_lds16(kbuf + (size_t)(b * Sz + kt * 128 + key) * Dz + h * DHz +
                     kchunk * 8,
                 Ks + wave * 2048 + j * 512);
      const int dh = wave * 16 + j * 4 + (lane >> 4);
      const int vchunk = (lane & 15) ^ (dh & 7);
      load_lds16(vt + vbase + (size_t)dh * Sz + kt * 128 + vchunk * 8,
                 Vs + wave * 2048 + j * 512);
    }
    __syncthreads();

    floatx4 z[8];
#pragma unroll
    for (int t = 0; t < 8; ++t) {
      const int krow = t * 16 + l15;
      bf16x8 fk0 = ld8(&Ks[krow * 64 + s0q * 8]);
      bf16x8 fk1 = ld8(&Ks[krow * 64 + (s0q ^ 4) * 8]);
      floatx4 zz = {0.f, 0.f, 0.f, 0.f};
      zz = __builtin_amdgcn_mfma_f32_16x16x32_bf16(fk0, fq0, zz, 0, 0, 0);
      zz = __builtin_amdgcn_mfma_f32_16x16x32_bf16(fk1, fq1, zz, 0, 0, 0);
      const float4 ad =
          *reinterpret_cast<const float4*>(&addend[kt * 128 + t * 16 + quad * 4]);
      z[t][0] = zz[0] * 0.125f + ad.x;
      z[t][1] = zz[1] * 0.125f + ad.y;
      z[t][2] = zz[2] * 0.125f + ad.z;
      z[t][3] = zz[3] * 0.125f + ad.w;
    }
    float mx = z[0][0];
#pragma unroll
    for (int t = 0; t < 8; ++t)
#pragma unroll
      for (int r = 0; r < 4; ++r) mx = fmaxf(mx, z[t][r]);
    mx = fmaxf(mx, __shfl_xor(mx, 16, 64));
    mx = fmaxf(mx, __shfl_xor(mx, 32, 64));
    const float nm = fmaxf(m_l, mx);
    const float alpha = __expf(m_l - nm);
    m_l = nm;
    float su = 0.f;
#pragma unroll
    for (int t = 0; t < 8; ++t) {
      union { u16 s[4]; uint2 u; } pk;
#pragma unroll
      for (int r = 0; r < 4; ++r) {
        float p = __expf(z[t][r] - nm);
        su += p;
        pk.s[r] = f2b(p);
      }
      *reinterpret_cast<uint2*>(&P[wave][l15][t * 16 + quad * 4]) = pk.u;
    }
    su += __shfl_xor(su, 16, 64);
    su += __shfl_xor(su, 32, 64);
    l_l = l_l * alpha + su;
    float av[4];
#pragma unroll
    for (int r = 0; r < 4; ++r) av[r] = __shfl(alpha, quad * 4 + r, 64);
#pragma unroll
    for (int nt = 0; nt < 4; ++nt)
#pragma unroll
      for (int r = 0; r < 4; ++r) o[nt][r] *= av[r];
    bf16x8 ap[4];
#pragma unroll
    for (int c = 0; c < 4; ++c)
      ap[c] = ld8(&P[wave][l15][c * 32 + quad * 8]);
#pragma unroll
    for (int nt = 0; nt < 4; ++nt) {
#pragma unroll
      for (int c = 0; c < 4; ++c) {
        bf16x8 bv =
            ld8(&Vs[(nt * 16 + l15) * 128 + (((c * 4 + quad) ^ l7) * 8)]);
        o[nt] = __builtin_amdgcn_mfma_f32_16x16x32_bf16(ap[c], bv, o[nt], 0, 0, 0);
      }
    }
  }

  const float linv = 1.f / l_l;
  float lv[4];
#pragma unroll
  for (int r = 0; r < 4; ++r) lv[r] = __shfl(linv, quad * 4 + r, 64);
  const int qr = bq * 64 + wave * 16 + quad * 4;
#pragma unroll
  for (int nt = 0; nt < 4; ++nt)
#pragma unroll
    for (int r = 0; r < 4; ++r) {
      float v = o[nt][r] * lv[r];
      ctx[(size_t)(b * Sz + qr + r) * Dz + h * DHz + nt * 16 + l15] = f2b(v);
    }
}

// ---------------- layernorm (row = 768) ----------------
__global__ __launch_bounds__(256)
void ln_k(const float* __restrict__ in, const float* __restrict__ g,
          const float* __restrict__ be, float* __restrict__ outF,
          u16* __restrict__ outB) {
  const int row = blockIdx.x;
  const float* x = in + (size_t)row * Dz;
  const int tid = threadIdx.x;
  float v0 = x[tid], v1 = x[tid + 256], v2 = x[tid + 512];
  float s = v0 + v1 + v2;
  float s2 = v0 * v0 + v1 * v1 + v2 * v2;
#pragma unroll
  for (int off = 1; off < 64; off <<= 1) {
    s += __shfl_xor(s, off, 64);
    s2 += __shfl_xor(s2, off, 64);
  }
  __shared__ float red[8];
  int wave = tid >> 6, lane = tid & 63;
  if (lane == 0) { red[wave] = s; red[4 + wave] = s2; }
  __syncthreads();
  s = red[0] + red[1] + red[2] + red[3];
  s2 = red[4] + red[5] + red[6] + red[7];
  const float mu = s * (1.f / 768.f);
  const float rstd = rsqrtf(s2 * (1.f / 768.f) - mu * mu + 1e-5f);
  float vv[3] = {v0, v1, v2};
#pragma unroll
  for (int e = 0; e < 3; ++e) {
    int col = tid + e * 256;
    float y = (vv[e] - mu) * rstd * g[col] + be[col];
    outF[(size_t)row * Dz + col] = y;
    if (outB) outB[(size_t)row * Dz + col] = f2b(y);
  }
}

// ---------------- launch ----------------
extern "C" void kernel_launch(void* const* d_in, const int* in_sizes, int n_in,
                              void* d_out, int out_size, void* d_ws,
                              size_t ws_size, hipStream_t stream) {
  const float* x   = (const float*)d_in[0];
  const int*   msk = (const int*)d_in[1];
  const float* Wq  = (const float*)d_in[2];
  const float* bq  = (const float*)d_in[3];
  const float* Wk  = (const float*)d_in[4];
  const float* bk  = (const float*)d_in[5];
  const float* Wv  = (const float*)d_in[6];
  const float* bv  = (const float*)d_in[7];
  const float* Wo  = (const float*)d_in[8];
  const float* bo  = (const float*)d_in[9];
  const float* g1  = (const float*)d_in[10];
  const float* be1 = (const float*)d_in[11];
  const float* W1  = (const float*)d_in[12];
  const float* b1  = (const float*)d_in[13];
  const float* W2  = (const float*)d_in[14];
  const float* b2  = (const float*)d_in[15];
  const float* g2  = (const float*)d_in[16];
  const float* be2 = (const float*)d_in[17];
  float* out = (float*)d_out;

  char* ws = (char*)d_ws;
  u16*   xb    = (u16*)(ws + 0);
  u16*   wqkvb = (u16*)(ws + 12582912);   // [2304][768] bf16 (transposed)
  u16*   wob   = (u16*)(ws + 16121856);   // [768][768]
  u16*   w1b   = (u16*)(ws + 17301504);   // [1536][768]
  u16*   w2b   = (u16*)(ws + 19660800);   // [768][1536]
  u16*   qb    = (u16*)(ws + 22020096);
  u16*   kb    = (u16*)(ws + 34603008);
  u16*   vtb   = (u16*)(ws + 47185920);
  u16*   ctx   = (u16*)(ws + 59768832);
  float* att   = (float*)(ws + 72351744);
  float* hf    = (float*)(ws + 97517568);
  u16*   hb    = (u16*)(ws + 122683392);
  u16*   f1    = (u16*)(ws + 47185920);  // reuse vt+ctx (dead after O-proj)
  float* yy    = (float*)(ws + 22020096); // reuse q+k (dead after attention)

  cvt4<<<6291456 / 4 / 256, 256, 0, stream>>>(x, xb, 6291456 / 4);
  wtrans<<<dim3(2304 / 32, 768 / 32), 256, 0, stream>>>(Wq, Wk, Wv, wqkvb, 768,
                                                        2304, 768);
  wtrans<<<dim3(24, 24), 256, 0, stream>>>(Wo, nullptr, nullptr, wob, 768, 768,
                                           768);
  wtrans<<<dim3(48, 24), 256, 0, stream>>>(W1, nullptr, nullptr, w1b, 768, 1536,
                                           1536);
  wtrans<<<dim3(24, 48), 256, 0, stream>>>(W2, nullptr, nullptr, w2b, 1536, 768,
                                           768);

  // QKV: [8192x768] @ [768x2304]
  gemm_k<0><<<dim3(2304 / 128, 8192 / 128), 256, 0, stream>>>(
      xb, wqkvb, 8192, 2304, 768, bq, bk, bv, nullptr, nullptr, nullptr, qb, kb,
      vtb);
  // attention
  attn_k<<<dim3(Sz / 64, Bz * Hz), 256, 0, stream>>>(qb, kb, vtb, msk, ctx);
  // O-proj + residual x -> att (fp32)
  gemm_k<1><<<dim3(768 / 128, 8192 / 128), 256, 0, stream>>>(
      ctx, wob, 8192, 768, 768, bo, nullptr, nullptr, x, att, nullptr, nullptr,
      nullptr, nullptr);
  // LN1 -> hf (fp32) + hb (bf16)
  ln_k<<<8192, 256, 0, stream>>>(att, g1, be1, hf, hb);
  // FFN1 + relu -> f1 (bf16)
  gemm_k<2><<<dim3(1536 / 128, 8192 / 128), 256, 0, stream>>>(
      hb, w1b, 8192, 1536, 768, b1, nullptr, nullptr, nullptr, nullptr, f1,
      nullptr, nullptr, nullptr);
  // FFN2 + residual hf -> yy (fp32)
  gemm_k<1><<<dim3(768 / 128, 8192 / 128), 256, 0, stream>>>(
      f1, w2b, 8192, 768, 1536, b2, nullptr, nullptr, hf, yy, nullptr, nullptr,
      nullptr, nullptr);
  // LN2 -> out
  ln_k<<<8192, 256, 0, stream>>>(yy, g2, be2, out, nullptr);
}

// Round 2
// 357.833 us; speedup vs baseline: 1.0841x; 1.0308x over previous
//
#include <hip/hip_runtime.h>
#include <cstdint>
#include <cstddef>

typedef unsigned short u16;
typedef __attribute__((ext_vector_type(8))) __bf16 bf16x8;
typedef __attribute__((ext_vector_type(4))) float floatx4;

#define Bz 8
#define Sz 1024
#define Dz 768
#define Hz 12
#define DHz 64

__device__ __forceinline__ u16 f2b(float f) {
  unsigned u = __float_as_uint(f);
  return (u16)((u + 0x7fffu + ((u >> 16) & 1u)) >> 16);
}

// hardware RNE f32->bf16 (compiler emits v_cvt_pk_bf16_f32 for pairs)
__device__ __forceinline__ u16 f2b_hw(float f) {
  __bf16 h = (__bf16)f;
  return __builtin_bit_cast(u16, h);
}

__device__ __forceinline__ bf16x8 ld8(const u16* p) {
  union { uint4 u; bf16x8 b; } t;
  t.u = *reinterpret_cast<const uint4*>(p);
  return t.b;
}

// async global->LDS, 16B per lane; lds base must be wave-uniform (HW adds lane*16)
__device__ __forceinline__ void load_lds16(const u16* g, u16* l) {
  __builtin_amdgcn_global_load_lds(
      (const __attribute__((address_space(1))) unsigned int*)g,
      (__attribute__((address_space(3))) unsigned int*)l, 16, 0, 0);
}

// ---------------- conversions ----------------
__global__ __launch_bounds__(256) void cvt4(const float* __restrict__ src,
                                            u16* __restrict__ dst, int n4) {
  int i = blockIdx.x * 256 + threadIdx.x;
  if (i >= n4) return;
  float4 v = reinterpret_cast<const float4*>(src)[i];
  union { u16 s[4]; uint2 u; } t;
  t.s[0] = f2b(v.x); t.s[1] = f2b(v.y); t.s[2] = f2b(v.z); t.s[3] = f2b(v.w);
  reinterpret_cast<uint2*>(dst)[i] = t.u;
}

// transpose fp32 [K][N] -> bf16 [N][K]; for QKV pack s1/s2 select by column
__global__ __launch_bounds__(256)
void wtrans(const float* __restrict__ s0, const float* __restrict__ s1,
            const float* __restrict__ s2, u16* __restrict__ dst,
            int K, int N, int srcN) {
  __shared__ float T[32][33];
  const int tx = threadIdx.x & 31, ty = threadIdx.x >> 5;
  const int n0 = blockIdx.x * 32, k0 = blockIdx.y * 32;
  const int n = n0 + tx;
  const float* src = s0;
  int nn = n;
  if (s1 && n >= 1536) { src = s2; nn = n - 1536; }
  else if (s1 && n >= 768) { src = s1; nn = n - 768; }
#pragma unroll
  for (int i = 0; i < 4; ++i)
    T[ty + i * 8][tx] = src[(size_t)(k0 + ty + i * 8) * srcN + nn];
  __syncthreads();
#pragma unroll
  for (int i = 0; i < 4; ++i)
    dst[(size_t)(n0 + ty + i * 8) * K + k0 + tx] = f2b(T[tx][ty + i * 8]);
}

// ---------------- GEMM (B^T input): C = A(MxK) * Bt(NxK)^T + epilogue ------
// 3-buffer LDS, 2-tiles-ahead prefetch, counted s_waitcnt vmcnt(4) at the
// loop head (vmcnt(0) only on the final iteration).  Prefetch stays BELOW the
// frag ds_reads.  Bank-conflict fix: pre-swizzled global source chunk
// (lane&3)^((lane>>3)&3) + matching read-side XOR.  Bijective XCD swizzle.
// EPI 0: QKV scatter; EPI 1: bias0 + resid (fp32) -> outF; EPI 2: bias0+relu->outB
template <int EPI>
__global__ __launch_bounds__(256, 3)
void gemm_k(const u16* __restrict__ A, const u16* __restrict__ Bt,
            int M, int N, int K,
            const float* __restrict__ bias0, const float* __restrict__ bias1,
            const float* __restrict__ bias2, const float* __restrict__ resid,
            float* __restrict__ outF, u16* __restrict__ outB,
            u16* __restrict__ qO, u16* __restrict__ kO, u16* __restrict__ vtO) {
  __shared__ __align__(16) u16 As[3][128 * 32];
  __shared__ __align__(16) u16 Bs[3][128 * 32];
  const int tid = threadIdx.x;
  const int lane = tid & 63, wave = tid >> 6;
  const int l15 = lane & 15, quad = lane >> 4;

  // bijective XCD-aware remap of the linear workgroup id
  const int nx = gridDim.x;
  const int nwg = nx * gridDim.y;
  const int lin = blockIdx.y * nx + blockIdx.x;
  const int swz = (lin & 7) * (nwg >> 3) + (lin >> 3);
  const int bx = swz % nx, by = swz / nx;

  const int m0 = by * 128, n0 = bx * 128;
  const int wm = (wave >> 1) * 64, wn = (wave & 1) * 64;

  floatx4 acc[4][4];
#pragma unroll
  for (int i = 0; i < 4; ++i)
#pragma unroll
    for (int j = 0; j < 4; ++j) acc[i][j] = {0.f, 0.f, 0.f, 0.f};

  const int srow = lane >> 2;          // + (wave*2+j)*16
  const int scol = (((lane & 3) ^ ((lane >> 3) & 3))) * 8;
  const u16* pA = A + (size_t)(m0 + wave * 32 + srow) * K + scol;
  const u16* pB = Bt + (size_t)(n0 + wave * 32 + srow) * K + scol;

  // prologue: stage tiles 0 and 1 into bufs 0,1
#pragma unroll
  for (int t = 0; t < 2; ++t)
#pragma unroll
    for (int j = 0; j < 2; ++j) {
      load_lds16(pA + (size_t)(j * 16) * K + t * 32, &As[t][(wave * 2 + j) * 512]);
      load_lds16(pB + (size_t)(j * 16) * K + t * 32, &Bs[t][(wave * 2 + j) * 512]);
    }

  const int NIT = K >> 5;
  const int rsw = (l15 >> 1) & 3;      // read-side bank swizzle key
  int cur = 0;
  for (int i = 0; i < NIT; ++i) {
    if (i == NIT - 1) asm volatile("s_waitcnt vmcnt(0)" ::: "memory");
    else              asm volatile("s_waitcnt vmcnt(4)" ::: "memory");
    __builtin_amdgcn_s_barrier();
    bf16x8 af[4], bf[4];
#pragma unroll
    for (int ii = 0; ii < 4; ++ii)
      af[ii] = ld8(&As[cur][(wm + ii * 16 + l15) * 32 + (quad ^ rsw) * 8]);
#pragma unroll
    for (int j = 0; j < 4; ++j)
      bf[j] = ld8(&Bs[cur][(wn + j * 16 + l15) * 32 + (quad ^ rsw) * 8]);
    __builtin_amdgcn_sched_barrier(0);
    if (i + 2 < NIT) {
      const int k2 = (i + 2) << 5;
      int pf = cur + 2; if (pf >= 3) pf -= 3;
#pragma unroll
      for (int j = 0; j < 2; ++j) {
        load_lds16(pA + (size_t)(j * 16) * K + k2, &As[pf][(wave * 2 + j) * 512]);
        load_lds16(pB + (size_t)(j * 16) * K + k2, &Bs[pf][(wave * 2 + j) * 512]);
      }
    }
    __builtin_amdgcn_sched_barrier(0);
#pragma unroll
    for (int ii = 0; ii < 4; ++ii)
#pragma unroll
      for (int j = 0; j < 4; ++j)
        acc[ii][j] = __builtin_amdgcn_mfma_f32_16x16x32_bf16(af[ii], bf[j],
                                                             acc[ii][j], 0, 0, 0);
    cur += 1; if (cur == 3) cur = 0;
  }

#pragma unroll
  for (int i = 0; i < 4; ++i) {
    int mbase = m0 + wm + i * 16 + quad * 4;
#pragma unroll
    for (int j = 0; j < 4; ++j) {
      int n = n0 + wn + j * 16 + l15;
#pragma unroll
      for (int r = 0; r < 4; ++r) {
        int mm = mbase + r;
        float v = acc[i][j][r];
        if (EPI == 0) {
          if (n < 768) {
            v += bias0[n];
            qO[(size_t)mm * 768 + n] = f2b(v);
          } else if (n < 1536) {
            v += bias1[n - 768];
            kO[(size_t)mm * 768 + (n - 768)] = f2b(v);
          } else {
            int d = n - 1536;
            v += bias2[d];
            int hh = d >> 6, dh = d & 63;
            int bb = mm >> 10, ss = mm & 1023;
            vtO[((size_t)(bb * Hz + hh) * DHz + dh) * Sz + ss] = f2b(v);
          }
        } else if (EPI == 1) {
          v += bias0[n] + resid[(size_t)mm * N + n];
          outF[(size_t)mm * N + n] = v;
        } else {
          v += bias0[n];
          v = fmaxf(v, 0.f);
          outB[(size_t)mm * N + n] = f2b(v);
        }
      }
    }
  }
}

// ---------------- flash attention (double-buffered 64-key K/V tiles) -------
// R7: KVBLK 128->64, 2 LDS buffers, ONE barrier per tile, tile kt+1 staged
// right after tile kt's K/V frag reads (proven loads-below-ds_reads order),
// explicit vmcnt(0) only at loop head -> each tile's 4 global_load_lds have a
// full iteration (~1k cyc) of compute as latency slack instead of zero.
// LDS 45.6KB -> 3 blocks/CU.  T13 defer-max skips the o-rescale (+4 shuffles)
// when no q-row's tile max exceeds m+8 (exact math when taken, P <= e^8).
__global__ __launch_bounds__(256, 3)
void attn_k(const u16* __restrict__ q, const u16* __restrict__ kbuf,
            const u16* __restrict__ vt, const int* __restrict__ mask,
            u16* __restrict__ ctx) {
  __shared__ float addend[Sz];
  __shared__ __align__(16) u16 Ks[2][64 * 64];
  __shared__ __align__(16) u16 Vs[2][64 * 64];
  __shared__ __align__(16) u16 P[4][16][68];
  const int tid = threadIdx.x;
  const int wave = tid >> 6, lane = tid & 63;
  const int l15 = lane & 15, quad = lane >> 4;
  // bijective XCD swizzle: grid (16,96) = 1536 wgs; 192 consecutive per XCD
  const int lin = blockIdx.y * 16 + blockIdx.x;
  const int swzid = (lin & 7) * 192 + (lin >> 3);
  const int bq = swzid & 15;
  const int bh = swzid >> 4;
  const int b = bh / Hz, h = bh - b * Hz;

  for (int s = tid; s < Sz; s += 256)
    addend[s] = mask[b * Sz + s] ? 0.f : -1e9f;

  const int qrow = bq * 64 + wave * 16 + l15;
  const u16* qp = q + (size_t)(b * Sz + qrow) * Dz + h * DHz;
  const bf16x8 fq0 = ld8(qp + quad * 8);
  const bf16x8 fq1 = ld8(qp + 32 + quad * 8);

  const int l7 = l15 & 7;
  const int s0q = quad ^ l7;

  // staging geometry (per thread): row srow in 0..31 (+32 for round 1),
  // chunk position spos; stored chunk = spos ^ (row&7) (bank swizzle).
  const int srow = tid >> 3;
  const int spos = tid & 7;
  const int schunk = spos ^ (srow & 7);
  const u16* kg = kbuf + (size_t)(b * Sz + srow) * Dz + h * DHz + schunk * 8;
  const u16* vg = vt + (size_t)(b * Hz + h) * (DHz * Sz) + (size_t)srow * Sz +
                  schunk * 8;

  float m_l = -1e30f, l_l = 0.f;
  floatx4 o[4];
#pragma unroll
  for (int nt = 0; nt < 4; ++nt) o[nt] = {0.f, 0.f, 0.f, 0.f};

  // prologue: stage tile 0 into buf 0 (K j0, K j1, V j0, V j1)
  load_lds16(kg, &Ks[0][wave * 512]);
  load_lds16(kg + (size_t)32 * Dz, &Ks[0][2048 + wave * 512]);
  load_lds16(vg, &Vs[0][wave * 512]);
  load_lds16(vg + (size_t)32 * Sz, &Vs[0][2048 + wave * 512]);

  for (int kt = 0; kt < 16; ++kt) {
    const int cur = kt & 1;
    // own tile-kt staging complete (issued one full iteration ago)
    asm volatile("s_waitcnt vmcnt(0)" ::: "memory");
    __builtin_amdgcn_s_barrier();
    // K fragments for this tile (all LDS reads of buf[cur] that must precede
    // the prefetch issue stay above it)
    bf16x8 fk0[4], fk1[4];
#pragma unroll
    for (int t = 0; t < 4; ++t) {
      const int krow = t * 16 + l15;
      fk0[t] = ld8(&Ks[cur][krow * 64 + s0q * 8]);
      fk1[t] = ld8(&Ks[cur][krow * 64 + (s0q ^ 4) * 8]);
    }
    __builtin_amdgcn_sched_barrier(0);
    if (kt + 1 < 16) {
      const size_t ko = (size_t)(kt + 1) * 64 * Dz;
      const int ve = (kt + 1) * 64;
      const int nb = cur ^ 1;
      load_lds16(kg + ko, &Ks[nb][wave * 512]);
      load_lds16(kg + ko + (size_t)32 * Dz, &Ks[nb][2048 + wave * 512]);
      load_lds16(vg + ve, &Vs[nb][wave * 512]);
      load_lds16(vg + ve + (size_t)32 * Sz, &Vs[nb][2048 + wave * 512]);
    }
    __builtin_amdgcn_sched_barrier(0);

    // QK^T (rows = keys, cols = q)
    floatx4 z[4];
#pragma unroll
    for (int t = 0; t < 4; ++t) {
      floatx4 zz = {0.f, 0.f, 0.f, 0.f};
      zz = __builtin_amdgcn_mfma_f32_16x16x32_bf16(fk0[t], fq0, zz, 0, 0, 0);
      zz = __builtin_amdgcn_mfma_f32_16x16x32_bf16(fk1[t], fq1, zz, 0, 0, 0);
      const float4 ad =
          *reinterpret_cast<const float4*>(&addend[kt * 64 + t * 16 + quad * 4]);
      z[t][0] = zz[0] * 0.125f + ad.x;
      z[t][1] = zz[1] * 0.125f + ad.y;
      z[t][2] = zz[2] * 0.125f + ad.z;
      z[t][3] = zz[3] * 0.125f + ad.w;
    }
    float mx = fmaxf(fmaxf(z[0][0], z[0][1]), fmaxf(z[0][2], z[0][3]));
#pragma unroll
    for (int t = 1; t < 4; ++t)
      mx = fmaxf(mx, fmaxf(fmaxf(z[t][0], z[t][1]), fmaxf(z[t][2], z[t][3])));
    mx = fmaxf(mx, __shfl_xor(mx, 16, 64));
    mx = fmaxf(mx, __shfl_xor(mx, 32, 64));
    // T13 defer-max: rescale only when some row's max grew past m+8
    if (!__all(mx <= m_l + 8.f)) {
      const float nm = fmaxf(m_l, mx);
      const float alpha = __expf(m_l - nm);
      m_l = nm;
      l_l *= alpha;
      float av[4];
#pragma unroll
      for (int r = 0; r < 4; ++r) av[r] = __shfl(alpha, quad * 4 + r, 64);
#pragma unroll
      for (int nt = 0; nt < 4; ++nt)
#pragma unroll
        for (int r = 0; r < 4; ++r) o[nt][r] *= av[r];
    }
    float su = 0.f;
#pragma unroll
    for (int t = 0; t < 4; ++t) {
      union { u16 s[4]; uint2 u; } pk;
#pragma unroll
      for (int r = 0; r < 4; ++r) {
        float p = __expf(z[t][r] - m_l);
        su += p;
        pk.s[r] = f2b_hw(p);
      }
      *reinterpret_cast<uint2*>(&P[wave][l15][t * 16 + quad * 4]) = pk.u;
    }
    su += __shfl_xor(su, 16, 64);
    su += __shfl_xor(su, 32, 64);
    l_l += su;
    // PV: P as A-operand (rows = q), V^T as B-operand (cols = dh)
    const bf16x8 ap0 = ld8(&P[wave][l15][quad * 8]);
    const bf16x8 ap1 = ld8(&P[wave][l15][32 + quad * 8]);
#pragma unroll
    for (int nt = 0; nt < 4; ++nt) {
      bf16x8 bv0 = ld8(&Vs[cur][(nt * 16 + l15) * 64 + ((quad ^ l7) * 8)]);
      bf16x8 bv1 = ld8(&Vs[cur][(nt * 16 + l15) * 64 + (((4 + quad) ^ l7) * 8)]);
      o[nt] = __builtin_amdgcn_mfma_f32_16x16x32_bf16(ap0, bv0, o[nt], 0, 0, 0);
      o[nt] = __builtin_amdgcn_mfma_f32_16x16x32_bf16(ap1, bv1, o[nt], 0, 0, 0);
    }
  }

  const float linv = 1.f / l_l;
  float lv[4];
#pragma unroll
  for (int r = 0; r < 4; ++r) lv[r] = __shfl(linv, quad * 4 + r, 64);
  const int qr = bq * 64 + wave * 16 + quad * 4;
#pragma unroll
  for (int nt = 0; nt < 4; ++nt)
#pragma unroll
    for (int r = 0; r < 4; ++r) {
      float v = o[nt][r] * lv[r];
      ctx[(size_t)(b * Sz + qr + r) * Dz + h * DHz + nt * 16 + l15] = f2b(v);
    }
}

// ---------------- layernorm (row = 768) ----------------
__global__ __launch_bounds__(256)
void ln_k(const float* __restrict__ in, const float* __restrict__ g,
          const float* __restrict__ be, float* __restrict__ outF,
          u16* __restrict__ outB) {
  const int row = blockIdx.x;
  const float* x = in + (size_t)row * Dz;
  const int tid = threadIdx.x;
  float v0 = x[tid], v1 = x[tid + 256], v2 = x[tid + 512];
  float s = v0 + v1 + v2;
  float s2 = v0 * v0 + v1 * v1 + v2 * v2;
#pragma unroll
  for (int off = 1; off < 64; off <<= 1) {
    s += __shfl_xor(s, off, 64);
    s2 += __shfl_xor(s2, off, 64);
  }
  __shared__ float red[8];
  int wave = tid >> 6, lane = tid & 63;
  if (lane == 0) { red[wave] = s; red[4 + wave] = s2; }
  __syncthreads();
  s = red[0] + red[1] + red[2] + red[3];
  s2 = red[4] + red[5] + red[6] + red[7];
  const float mu = s * (1.f / 768.f);
  const float rstd = rsqrtf(s2 * (1.f / 768.f) - mu * mu + 1e-5f);
  float vv[3] = {v0, v1, v2};
#pragma unroll
  for (int e = 0; e < 3; ++e) {
    int col = tid + e * 256;
    float y = (vv[e] - mu) * rstd * g[col] + be[col];
    outF[(size_t)row * Dz + col] = y;
    if (outB) outB[(size_t)row * Dz + col] = f2b(y);
  }
}

// ---------------- launch ----------------
extern "C" void kernel_launch(void* const* d_in, const int* in_sizes, int n_in,
                              void* d_out, int out_size, void* d_ws,
                              size_t ws_size, hipStream_t stream) {
  const float* x   = (const float*)d_in[0];
  const int*   msk = (const int*)d_in[1];
  const float* Wq  = (const float*)d_in[2];
  const float* bq  = (const float*)d_in[3];
  const float* Wk  = (const float*)d_in[4];
  const float* bk  = (const float*)d_in[5];
  const float* Wv  = (const float*)d_in[6];
  const float* bv  = (const float*)d_in[7];
  const float* Wo  = (const float*)d_in[8];
  const float* bo  = (const float*)d_in[9];
  const float* g1  = (const float*)d_in[10];
  const float* be1 = (const float*)d_in[11];
  const float* W1  = (const float*)d_in[12];
  const float* b1  = (const float*)d_in[13];
  const float* W2  = (const float*)d_in[14];
  const float* b2  = (const float*)d_in[15];
  const float* g2  = (const float*)d_in[16];
  const float* be2 = (const float*)d_in[17];
  float* out = (float*)d_out;

  char* ws = (char*)d_ws;
  u16*   xb    = (u16*)(ws + 0);
  u16*   wqkvb = (u16*)(ws + 12582912);   // [2304][768] bf16 (transposed)
  u16*   wob   = (u16*)(ws + 16121856);   // [768][768]
  u16*   w1b   = (u16*)(ws + 17301504);   // [1536][768]
  u16*   w2b   = (u16*)(ws + 19660800);   // [768][1536]
  u16*   qb    = (u16*)(ws + 22020096);
  u16*   kb    = (u16*)(ws + 34603008);
  u16*   vtb   = (u16*)(ws + 47185920);
  u16*   ctx   = (u16*)(ws + 59768832);
  float* att   = (float*)(ws + 72351744);
  float* hf    = (float*)(ws + 97517568);
  u16*   hb    = (u16*)(ws + 122683392);
  u16*   f1    = (u16*)(ws + 47185920);  // reuse vt+ctx (dead after O-proj)
  float* yy    = (float*)(ws + 22020096); // reuse q+k (dead after attention)

  cvt4<<<6291456 / 4 / 256, 256, 0, stream>>>(x, xb, 6291456 / 4);
  wtrans<<<dim3(2304 / 32, 768 / 32), 256, 0, stream>>>(Wq, Wk, Wv, wqkvb, 768,
                                                        2304, 768);
  wtrans<<<dim3(24, 24), 256, 0, stream>>>(Wo, nullptr, nullptr, wob, 768, 768,
                                           768);
  wtrans<<<dim3(48, 24), 256, 0, stream>>>(W1, nullptr, nullptr, w1b, 768, 1536,
                                           1536);
  wtrans<<<dim3(24, 48), 256, 0, stream>>>(W2, nullptr, nullptr, w2b, 1536, 768,
                                           768);

  // QKV: [8192x768] @ [768x2304]
  gemm_k<0><<<dim3(2304 / 128, 8192 / 128), 256, 0, stream>>>(
      xb, wqkvb, 8192, 2304, 768, bq, bk, bv, nullptr, nullptr, nullptr, qb, kb,
      vtb);
  // attention
  attn_k<<<dim3(Sz / 64, Bz * Hz), 256, 0, stream>>>(qb, kb, vtb, msk, ctx);
  // O-proj + residual x -> att (fp32)
  gemm_k<1><<<dim3(768 / 128, 8192 / 128), 256, 0, stream>>>(
      ctx, wob, 8192, 768, 768, bo, nullptr, nullptr, x, att, nullptr, nullptr,
      nullptr, nullptr);
  // LN1 -> hf (fp32) + hb (bf16)
  ln_k<<<8192, 256, 0, stream>>>(att, g1, be1, hf, hb);
  // FFN1 + relu -> f1 (bf16)
  gemm_k<2><<<dim3(1536 / 128, 8192 / 128), 256, 0, stream>>>(
      hb, w1b, 8192, 1536, 768, b1, nullptr, nullptr, nullptr, nullptr, f1,
      nullptr, nullptr, nullptr);
  // FFN2 + residual hf -> yy (fp32)
  gemm_k<1><<<dim3(768 / 128, 8192 / 128), 256, 0, stream>>>(
      f1, w2b, 8192, 768, 1536, b2, nullptr, nullptr, hf, yy, nullptr, nullptr,
      nullptr, nullptr);
  // LN2 -> out
  ln_k<<<8192, 256, 0, stream>>>(yy, g2, be2, out, nullptr);
}